// Round 7
// baseline (1588.706 us; speedup 1.0000x reference)
//
#include <hip/hip_runtime.h>

#define BATCH 8
#define NPTS 8192
#define NCH 64
#define NPOINT 1024
#define NSAMPLE 32

typedef float f4 __attribute__((ext_vector_type(4)));
typedef float f2 __attribute__((ext_vector_type(2)));

// DPP-based u64 max step: merge with the value DPP-shifted across lanes.
// bound_ctrl=false + old=self => invalid-source lanes self-merge (no-op).
template <int CTRL>
__device__ __forceinline__ unsigned long long dpp_max_u64(unsigned long long k) {
  int lo = (int)(unsigned int)k;
  int hi = (int)(unsigned int)(k >> 32);
  int slo = __builtin_amdgcn_update_dpp(lo, lo, CTRL, 0xf, 0xf, false);
  int shi = __builtin_amdgcn_update_dpp(hi, hi, CTRL, 0xf, 0xf, false);
  unsigned long long s =
      ((unsigned long long)(unsigned int)shi << 32) | (unsigned int)slo;
  return (s > k) ? s : k;
}

// ---------------------------------------------------------------------------
// Furthest point sampling: one block per batch, 512 threads (8 waves,
// 2 per SIMD). R6 post-mortem: at 1 wave/SIMD the ~1100 stall cyc/iter
// (LDS roundtrips, DPP chain, barrier skew) sit fully on the critical path.
// 2 waves/SIMD covers most of it for only ~25% more per-SIMD issue
// (8 f2 slots/thread halves the tie-scan). Structure otherwise identical
// to R6 (absmax 0.0 verified):
//  - interleaved ownership p = 2*tid + 1024*j (ds_read_b64 fill, 2-way free)
//  - exact contract(off) fp32 distance update, 16 points as 8 f2 slots
//  - value-only pk-max tree + thread-local scan (j desc, y then x) for the
//    lowest matching global index; exact argmax-first tie semantics
//  - wave argmax: 6 DPP u64-max steps, result in lane 63
//  - lane 63 writes {key, coords}; ONE barrier; all merge 8 entries
// ---------------------------------------------------------------------------
__global__ __launch_bounds__(512) void fps_kernel(const float* __restrict__ xyz,
                                                  float* __restrict__ newxyz) {
  const int b = blockIdx.x;
  const int tid = threadIdx.x;
  const int lane = tid & 63;
  const int wid = tid >> 6;  // 0..7
  const float* xb = xyz + (size_t)b * NPTS * 3;

  __shared__ float px_l[NPTS], py_l[NPTS], pz_l[NPTS];        // 96 KB SoA
  __shared__ __align__(16) unsigned long long pke[2][8][4];   // key, xy, z, pad
  __shared__ unsigned short winidx[NPOINT];

  // coalesced global -> LDS staging (lane-adjacent p => conflict-free writes)
  for (int p = tid; p < NPTS; p += 512) {
    px_l[p] = xb[p * 3 + 0];
    py_l[p] = xb[p * 3 + 1];
    pz_l[p] = xb[p * 3 + 2];
  }
  __syncthreads();

  // register fill from LDS: thread owns pairs (2t+1024j, 2t+1024j+1)
  f2 pxv[8], pyv[8], pzv[8], mindv[8];
#pragma unroll
  for (int j = 0; j < 8; ++j) {
    int p = 2 * tid + 1024 * j;
    pxv[j] = *(const f2*)&px_l[p];
    pyv[j] = *(const f2*)&py_l[p];
    pzv[j] = *(const f2*)&pz_l[p];
    mindv[j] = f2{1e10f, 1e10f};
  }
  float qx = px_l[0], qy = py_l[0], qz = pz_l[0];  // pivot = point 0

  for (int i = 1; i < NPOINT; ++i) {
#pragma clang fp contract(off)
    const int par = i & 1;
    f2 qx2 = f2{qx, qx}, qy2 = f2{qy, qy}, qz2 = f2{qz, qz};

    // distance update (exact ref order) + value-only pk-max tree
    f2 tmax;
#pragma unroll
    for (int j = 0; j < 8; ++j) {
      f2 dx = pxv[j] - qx2;
      f2 dy = pyv[j] - qy2;
      f2 dz = pzv[j] - qz2;
      f2 d = (dx * dx + dy * dy) + dz * dz;
      f2 m = __builtin_elementwise_min(mindv[j], d);
      mindv[j] = m;
      tmax = (j == 0) ? m : __builtin_elementwise_max(tmax, m);
    }
    float lmax = fmaxf(tmax.x, tmax.y);

    // thread-local lowest global index achieving lmax
    // global idx = 2*tid + 1024*j + k; scan j desc, y(k=1) then x(k=0)
    int c = 0;
#pragma unroll
    for (int j = 7; j >= 0; --j) {
      if (mindv[j].y == lmax) c = 2 * j + 1;
      if (mindv[j].x == lmax) c = 2 * j;
    }
    unsigned int gidx = (unsigned int)(2 * tid + ((c >> 1) << 10) + (c & 1));
    unsigned long long key =
        ((unsigned long long)__float_as_uint(lmax) << 32) |
        (unsigned long long)(~gidx);

    // wave argmax via DPP (VALU-speed), result valid in lane 63
    key = dpp_max_u64<0x111>(key);  // row_shr:1
    key = dpp_max_u64<0x112>(key);  // row_shr:2
    key = dpp_max_u64<0x114>(key);  // row_shr:4
    key = dpp_max_u64<0x118>(key);  // row_shr:8
    key = dpp_max_u64<0x142>(key);  // row_bcast:15
    key = dpp_max_u64<0x143>(key);  // row_bcast:31

    if (lane == 63) {
      unsigned int widx = ~(unsigned int)key;
      float wx = px_l[widx], wy = py_l[widx], wz = pz_l[widx];
      ulonglong2 e0;
      e0.x = key;
      e0.y = ((unsigned long long)__float_as_uint(wy) << 32) |
             (unsigned long long)__float_as_uint(wx);
      *(ulonglong2*)&pke[par][wid][0] = e0;
      pke[par][wid][2] = (unsigned long long)__float_as_uint(wz);
    }
    __syncthreads();

    // merge the 8 wave entries (broadcast LDS reads, b128)
    const ulonglong2* ew = (const ulonglong2*)&pke[par][0][0];
    ulonglong2 m0 = ew[0];                 // {key, xy}
    unsigned long long bz = ew[1].x;       // {z, pad}
#pragma unroll
    for (int w = 1; w < 8; ++w) {
      ulonglong2 t = ew[2 * w];
      unsigned long long tz = ew[2 * w + 1].x;
      if (t.x > m0.x) { m0 = t; bz = tz; }
    }
    qx = __uint_as_float((unsigned int)m0.y);
    qy = __uint_as_float((unsigned int)(m0.y >> 32));
    qz = __uint_as_float((unsigned int)bz);
    if (tid == 0) winidx[i] = (unsigned short)(~(unsigned int)m0.x);
  }

  __syncthreads();
  // write all 1024 sampled points from LDS
  for (int t = tid; t < NPOINT; t += 512) {
    const int idx = (t == 0) ? 0 : (int)winidx[t];
    float* op = newxyz + b * (NPOINT * 3) + t * 3;
    op[0] = px_l[idx];
    op[1] = py_l[idx];
    op[2] = pz_l[idx];
  }
}

// ---------------------------------------------------------------------------
// Ball query: one wave per (b, s) center. Ordered scan, first 32 indices with
// d2 < r^2; pad with first hit (0 if none). Exact fp32 distance arithmetic.
// ---------------------------------------------------------------------------
__global__ __launch_bounds__(256) void ball_kernel(const float* __restrict__ xyz,
                                                   const float* __restrict__ newxyz,
                                                   int* __restrict__ idxout) {
  const int lane = threadIdx.x & 63;
  const int pair = blockIdx.x * 4 + (threadIdx.x >> 6);
  const int b = pair >> 10;
  const float cx = newxyz[pair * 3 + 0];
  const float cy = newxyz[pair * 3 + 1];
  const float cz = newxyz[pair * 3 + 2];
  const float* xb = xyz + (size_t)b * NPTS * 3;
  int* op = idxout + pair * NSAMPLE;

  int cnt = 0;
  int first = 0;
  for (int base = 0; base < NPTS && cnt < NSAMPLE; base += 64) {
    const int p = base + lane;
    const float* pp = xb + p * 3;
    float dx = __fsub_rn(cx, pp[0]);
    float dy = __fsub_rn(cy, pp[1]);
    float dz = __fsub_rn(cz, pp[2]);
    float d2 = __fadd_rn(__fadd_rn(__fmul_rn(dx, dx), __fmul_rn(dy, dy)),
                         __fmul_rn(dz, dz));
    bool pred = d2 < 0.04f;  // strict <, RADIUS^2 in fp32
    unsigned long long m = __ballot(pred);
    if (cnt == 0 && m) first = base + __builtin_ctzll(m);
    int rank = cnt + (int)__popcll(m & ((1ull << lane) - 1ull));
    if (pred && rank < NSAMPLE) op[rank] = p;
    cnt += (int)__popcll(m);
  }
  if (cnt < NSAMPLE) {
    for (int r = cnt + lane; r < NSAMPLE; r += 64) op[r] = first;
  }
}

// ---------------------------------------------------------------------------
// Group + 3-layer MLP + max-pool. One block (256 thr) per (b, s) group.
// Weights staged transposed in LDS (wt[c][o]) so o-lanes read coalesced b128;
// x rows read as b128 broadcast. Register tiles: 4o x 2n (L1/L2), 4o x 4n (L3).
// LDS: xa 32x68 + xb 32x64 + wt 8192 floats = 48.5 KB -> 3 blocks/CU.
// ---------------------------------------------------------------------------
__global__ __launch_bounds__(256) void group_mlp_kernel(
    const float* __restrict__ xyz, const float* __restrict__ feat,
    const float* __restrict__ w0, const float* __restrict__ s0, const float* __restrict__ b0,
    const float* __restrict__ w1, const float* __restrict__ s1, const float* __restrict__ b1,
    const float* __restrict__ w2, const float* __restrict__ s2, const float* __restrict__ b2,
    const int* __restrict__ idxin, const float* __restrict__ newxyz,
    float* __restrict__ outf) {
  __shared__ float xa[32][68];  // layer0 input (3 xyz + 64 feat + 1 zero pad)
  __shared__ float xb[32][64];  // layer1 out; reused as max-reduce buffer
  __shared__ float wt[8192];    // transposed weights of current layer

  const int tid = threadIdx.x;
  const int pair = blockIdx.x;
  const int b = pair >> 10;
  const int s = pair & 1023;

  // ---- gather: 8 threads per sample row ----
  {
    const float cx = newxyz[pair * 3 + 0];
    const float cy = newxyz[pair * 3 + 1];
    const float cz = newxyz[pair * 3 + 2];
    const int n = tid >> 3, k8 = tid & 7;
    const int pid = idxin[pair * NSAMPLE + n];
    const float* fr = feat + ((size_t)(b * NPTS) + pid) * NCH + k8 * 8;
    f4 f0 = *(const f4*)fr;
    f4 f1 = *(const f4*)(fr + 4);
#pragma unroll
    for (int q = 0; q < 4; ++q) xa[n][3 + k8 * 8 + q] = f0[q];
#pragma unroll
    for (int q = 0; q < 4; ++q) xa[n][3 + k8 * 8 + 4 + q] = f1[q];
    if (k8 == 0) {
      const float* pr = xyz + ((size_t)(b * NPTS) + pid) * 3;
      xa[n][0] = pr[0] - cx;
      xa[n][1] = pr[1] - cy;
      xa[n][2] = pr[2] - cz;
      xa[n][67] = 0.f;
    }
  }
  // stage wT0: wt[c*64+o] = w0[o][c], c in [0,68) (c==67 zero pad)
  for (int t = tid; t < 68 * 64; t += 256) {
    int c = t >> 6, o = t & 63;
    wt[t] = (c < 67) ? w0[o * 67 + c] : 0.f;
  }
  __syncthreads();

  // ---- layer 1: K=68(pad), 64 out; xa -> xb ----
  {
    const int ot = tid & 15, nt = tid >> 4;
    float acc[2][4] = {};
    for (int c = 0; c < 68; c += 4) {
      f4 xq0 = *(const f4*)&xa[nt * 2 + 0][c];
      f4 xq1 = *(const f4*)&xa[nt * 2 + 1][c];
#pragma unroll
      for (int cc = 0; cc < 4; ++cc) {
        f4 wq = *(const f4*)&wt[(c + cc) * 64 + ot * 4];
#pragma unroll
        for (int i = 0; i < 4; ++i) {
          acc[0][i] = fmaf(xq0[cc], wq[i], acc[0][i]);
          acc[1][i] = fmaf(xq1[cc], wq[i], acc[1][i]);
        }
      }
    }
    f4 r0, r1;
#pragma unroll
    for (int i = 0; i < 4; ++i) {
      float sc = s0[ot * 4 + i], bi = b0[ot * 4 + i];
      r0[i] = fmaxf(fmaf(acc[0][i], sc, bi), 0.f);
      r1[i] = fmaxf(fmaf(acc[1][i], sc, bi), 0.f);
    }
    *(f4*)&xb[nt * 2 + 0][ot * 4] = r0;
    *(f4*)&xb[nt * 2 + 1][ot * 4] = r1;
  }
  __syncthreads();
  for (int t = tid; t < 64 * 64; t += 256) {
    int c = t >> 6, o = t & 63;
    wt[t] = w1[o * 64 + c];
  }
  __syncthreads();

  // ---- layer 2: K=64, 64 out; xb -> xa ----
  {
    const int ot = tid & 15, nt = tid >> 4;
    float acc[2][4] = {};
    for (int c = 0; c < 64; c += 4) {
      f4 xq0 = *(const f4*)&xb[nt * 2 + 0][c];
      f4 xq1 = *(const f4*)&xb[nt * 2 + 1][c];
#pragma unroll
      for (int cc = 0; cc < 4; ++cc) {
        f4 wq = *(const f4*)&wt[(c + cc) * 64 + ot * 4];
#pragma unroll
        for (int i = 0; i < 4; ++i) {
          acc[0][i] = fmaf(xq0[cc], wq[i], acc[0][i]);
          acc[1][i] = fmaf(xq1[cc], wq[i], acc[1][i]);
        }
      }
    }
    f4 r0, r1;
#pragma unroll
    for (int i = 0; i < 4; ++i) {
      float sc = s1[ot * 4 + i], bi = b1[ot * 4 + i];
      r0[i] = fmaxf(fmaf(acc[0][i], sc, bi), 0.f);
      r1[i] = fmaxf(fmaf(acc[1][i], sc, bi), 0.f);
    }
    *(f4*)&xa[nt * 2 + 0][ot * 4] = r0;
    *(f4*)&xa[nt * 2 + 1][ot * 4] = r1;
  }
  __syncthreads();
  for (int t = tid; t < 64 * 128; t += 256) {
    int c = t >> 7, o = t & 127;
    wt[t] = w2[o * 64 + c];
  }
  __syncthreads();

  // ---- layer 3: K=64, 128 out; xa -> per-thread max over 4 n ----
  {
    const int ot = tid & 31, nt = tid >> 5;
    float acc[4][4] = {};
    for (int c = 0; c < 64; c += 4) {
      f4 xq[4];
#pragma unroll
      for (int j = 0; j < 4; ++j) xq[j] = *(const f4*)&xa[nt * 4 + j][c];
#pragma unroll
      for (int cc = 0; cc < 4; ++cc) {
        f4 wq = *(const f4*)&wt[(c + cc) * 128 + ot * 4];
#pragma unroll
        for (int j = 0; j < 4; ++j) {
#pragma unroll
          for (int i = 0; i < 4; ++i)
            acc[j][i] = fmaf(xq[j][cc], wq[i], acc[j][i]);
        }
      }
    }
    f4 mx;
#pragma unroll
    for (int i = 0; i < 4; ++i) {
      float sc = s2[ot * 4 + i], bi = b2[ot * 4 + i];
      float v0 = fmaxf(fmaf(acc[0][i], sc, bi), 0.f);
      float v1 = fmaxf(fmaf(acc[1][i], sc, bi), 0.f);
      float v2 = fmaxf(fmaf(acc[2][i], sc, bi), 0.f);
      float v3 = fmaxf(fmaf(acc[3][i], sc, bi), 0.f);
      mx[i] = fmaxf(fmaxf(v0, v1), fmaxf(v2, v3));
    }
    float* red = &xb[0][0];  // xb free after layer2 barrier
    *(f4*)&red[nt * 128 + ot * 4] = mx;
    __syncthreads();
    if (tid < 128) {
      float m = red[tid];
#pragma unroll
      for (int w = 1; w < 8; ++w) m = fmaxf(m, red[w * 128 + tid]);
      outf[((size_t)(b * 128 + tid)) * 1024 + s] = m;
    }
  }
}

extern "C" void kernel_launch(void* const* d_in, const int* in_sizes, int n_in,
                              void* d_out, int out_size, void* d_ws, size_t ws_size,
                              hipStream_t stream) {
  const float* xyz = (const float*)d_in[0];
  const float* feat = (const float*)d_in[1];
  const float* w0 = (const float*)d_in[2];
  const float* s0 = (const float*)d_in[3];
  const float* b0 = (const float*)d_in[4];
  const float* w1 = (const float*)d_in[5];
  const float* s1 = (const float*)d_in[6];
  const float* b1 = (const float*)d_in[7];
  const float* w2 = (const float*)d_in[8];
  const float* s2 = (const float*)d_in[9];
  const float* b2 = (const float*)d_in[10];

  float* newxyz = (float*)d_out;                    // (8,1024,3)
  float* outf = (float*)d_out + BATCH * NPOINT * 3; // (8,128,1024)
  int* idxws = (int*)d_ws;                          // (8*1024, 32) ints = 1 MB

  fps_kernel<<<BATCH, 512, 0, stream>>>(xyz, newxyz);
  ball_kernel<<<(BATCH * NPOINT) / 4, 256, 0, stream>>>(xyz, newxyz, idxws);
  group_mlp_kernel<<<BATCH * NPOINT, 256, 0, stream>>>(
      xyz, feat, w0, s0, b0, w1, s1, b1, w2, s2, b2, idxws, newxyz, outf);
}

// Round 8
// 1423.227 us; speedup vs baseline: 1.1163x; 1.1163x over previous
//
#include <hip/hip_runtime.h>

#define BATCH 8
#define NPTS 8192
#define NCH 64
#define NPOINT 1024
#define NSAMPLE 32

typedef float f4 __attribute__((ext_vector_type(4)));
typedef float f2 __attribute__((ext_vector_type(2)));

// DPP-based u64 max step: merge with the value DPP-shifted across lanes.
// bound_ctrl=false + old=self => invalid-source lanes self-merge (no-op).
template <int CTRL>
__device__ __forceinline__ unsigned long long dpp_max_u64(unsigned long long k) {
  int lo = (int)(unsigned int)k;
  int hi = (int)(unsigned int)(k >> 32);
  int slo = __builtin_amdgcn_update_dpp(lo, lo, CTRL, 0xf, 0xf, false);
  int shi = __builtin_amdgcn_update_dpp(hi, hi, CTRL, 0xf, 0xf, false);
  unsigned long long s =
      ((unsigned long long)(unsigned int)shi << 32) | (unsigned int)slo;
  return (s > k) ? s : k;
}

// ---------------------------------------------------------------------------
// Furthest point sampling — EXACT R6 revert (measured 1042 us, absmax 0.0).
// 256 threads (4 waves, 1/SIMD) is the empirical optimum: R4 1024thr=1322,
// R6 256thr=1042, R7 512thr=1194 — the tail is block-convergent, extra waves
// only add merge work and barrier skew.
// ---------------------------------------------------------------------------
__global__ __launch_bounds__(256) void fps_kernel(const float* __restrict__ xyz,
                                                  float* __restrict__ newxyz) {
  const int b = blockIdx.x;
  const int tid = threadIdx.x;
  const int lane = tid & 63;
  const int wid = tid >> 6;  // 0..3
  const float* xb = xyz + (size_t)b * NPTS * 3;

  __shared__ float px_l[NPTS], py_l[NPTS], pz_l[NPTS];        // 96 KB SoA
  __shared__ __align__(16) unsigned long long pke[2][4][4];   // key, xy, z, pad
  __shared__ unsigned short winidx[NPOINT];

  // coalesced global -> LDS staging (lane-adjacent p => conflict-free writes)
  for (int p = tid; p < NPTS; p += 256) {
    px_l[p] = xb[p * 3 + 0];
    py_l[p] = xb[p * 3 + 1];
    pz_l[p] = xb[p * 3 + 2];
  }
  __syncthreads();

  // register fill from LDS: thread owns pairs (2t+512j, 2t+512j+1)
  f2 pxv[16], pyv[16], pzv[16], mindv[16];
#pragma unroll
  for (int j = 0; j < 16; ++j) {
    int p = 2 * tid + 512 * j;
    pxv[j] = *(const f2*)&px_l[p];
    pyv[j] = *(const f2*)&py_l[p];
    pzv[j] = *(const f2*)&pz_l[p];
    mindv[j] = f2{1e10f, 1e10f};
  }
  float qx = px_l[0], qy = py_l[0], qz = pz_l[0];  // pivot = point 0

  for (int i = 1; i < NPOINT; ++i) {
#pragma clang fp contract(off)
    const int par = i & 1;
    f2 qx2 = f2{qx, qx}, qy2 = f2{qy, qy}, qz2 = f2{qz, qz};

    // distance update (exact ref order) + value-only pk-max tree
    f2 tmax;
#pragma unroll
    for (int j = 0; j < 16; ++j) {
      f2 dx = pxv[j] - qx2;
      f2 dy = pyv[j] - qy2;
      f2 dz = pzv[j] - qz2;
      f2 d = (dx * dx + dy * dy) + dz * dz;
      f2 m = __builtin_elementwise_min(mindv[j], d);
      mindv[j] = m;
      tmax = (j == 0) ? m : __builtin_elementwise_max(tmax, m);
    }
    float lmax = fmaxf(tmax.x, tmax.y);

    // thread-local lowest global index achieving lmax
    // global idx = 2*tid + 512*j + k; scan j desc, y(k=1) then x(k=0)
    int c = 0;
#pragma unroll
    for (int j = 15; j >= 0; --j) {
      if (mindv[j].y == lmax) c = 2 * j + 1;
      if (mindv[j].x == lmax) c = 2 * j;
    }
    unsigned int gidx = (unsigned int)(2 * tid + ((c >> 1) << 9) + (c & 1));
    unsigned long long key =
        ((unsigned long long)__float_as_uint(lmax) << 32) |
        (unsigned long long)(~gidx);

    // wave argmax via DPP (VALU-speed), result valid in lane 63
    key = dpp_max_u64<0x111>(key);  // row_shr:1
    key = dpp_max_u64<0x112>(key);  // row_shr:2
    key = dpp_max_u64<0x114>(key);  // row_shr:4
    key = dpp_max_u64<0x118>(key);  // row_shr:8
    key = dpp_max_u64<0x142>(key);  // row_bcast:15
    key = dpp_max_u64<0x143>(key);  // row_bcast:31

    if (lane == 63) {
      unsigned int widx = ~(unsigned int)key;
      float wx = px_l[widx], wy = py_l[widx], wz = pz_l[widx];
      ulonglong2 e0;
      e0.x = key;
      e0.y = ((unsigned long long)__float_as_uint(wy) << 32) |
             (unsigned long long)__float_as_uint(wx);
      *(ulonglong2*)&pke[par][wid][0] = e0;
      pke[par][wid][2] = (unsigned long long)__float_as_uint(wz);
    }
    __syncthreads();

    // merge the 4 wave entries (broadcast LDS reads, b128)
    const ulonglong2* ew = (const ulonglong2*)&pke[par][0][0];
    ulonglong2 m0 = ew[0];                 // {key, xy}
    unsigned long long bz = ew[1].x;       // {z, pad}
#pragma unroll
    for (int w = 1; w < 4; ++w) {
      ulonglong2 t = ew[2 * w];
      unsigned long long tz = ew[2 * w + 1].x;
      if (t.x > m0.x) { m0 = t; bz = tz; }
    }
    qx = __uint_as_float((unsigned int)m0.y);
    qy = __uint_as_float((unsigned int)(m0.y >> 32));
    qz = __uint_as_float((unsigned int)bz);
    if (tid == 0) winidx[i] = (unsigned short)(~(unsigned int)m0.x);
  }

  __syncthreads();
  // write all 1024 sampled points from LDS
  for (int t = tid; t < NPOINT; t += 256) {
    const int idx = (t == 0) ? 0 : (int)winidx[t];
    float* op = newxyz + b * (NPOINT * 3) + t * 3;
    op[0] = px_l[idx];
    op[1] = py_l[idx];
    op[2] = pz_l[idx];
  }
}

// ---------------------------------------------------------------------------
// Ball query: one wave per (b, s) center. Ordered scan, first 32 indices with
// d2 < r^2; pad with first hit (0 if none). Exact fp32 distance arithmetic.
// ---------------------------------------------------------------------------
__global__ __launch_bounds__(256) void ball_kernel(const float* __restrict__ xyz,
                                                   const float* __restrict__ newxyz,
                                                   int* __restrict__ idxout) {
  const int lane = threadIdx.x & 63;
  const int pair = blockIdx.x * 4 + (threadIdx.x >> 6);
  const int b = pair >> 10;
  const float cx = newxyz[pair * 3 + 0];
  const float cy = newxyz[pair * 3 + 1];
  const float cz = newxyz[pair * 3 + 2];
  const float* xb = xyz + (size_t)b * NPTS * 3;
  int* op = idxout + pair * NSAMPLE;

  int cnt = 0;
  int first = 0;
  for (int base = 0; base < NPTS && cnt < NSAMPLE; base += 64) {
    const int p = base + lane;
    const float* pp = xb + p * 3;
    float dx = __fsub_rn(cx, pp[0]);
    float dy = __fsub_rn(cy, pp[1]);
    float dz = __fsub_rn(cz, pp[2]);
    float d2 = __fadd_rn(__fadd_rn(__fmul_rn(dx, dx), __fmul_rn(dy, dy)),
                         __fmul_rn(dz, dz));
    bool pred = d2 < 0.04f;  // strict <, RADIUS^2 in fp32
    unsigned long long m = __ballot(pred);
    if (cnt == 0 && m) first = base + __builtin_ctzll(m);
    int rank = cnt + (int)__popcll(m & ((1ull << lane) - 1ull));
    if (pred && rank < NSAMPLE) op[rank] = p;
    cnt += (int)__popcll(m);
  }
  if (cnt < NSAMPLE) {
    for (int r = cnt + lane; r < NSAMPLE; r += 64) op[r] = first;
  }
}

// ---------------------------------------------------------------------------
// Group + 3-layer MLP + max-pool. One block (256 thr) per (b, s) group.
// Same LDS layouts/tiling as R6, but inner loops use v_pk_fma_f32: acc packed
// as f2 over adjacent OUTPUT pairs (wq b128 loads give aligned o-pair VGPR
// pairs for free), x splatted {x,x} (op_sel-foldable). 25-50% VALU cut.
// fma contraction enabled in the MLP only (tolerance 5.4e-2; FPS stays exact).
// LDS: xa 32x68 + xb 32x64 + wt 8192 floats = 48.5 KB -> 3 blocks/CU.
// ---------------------------------------------------------------------------
__global__ __launch_bounds__(256) void group_mlp_kernel(
    const float* __restrict__ xyz, const float* __restrict__ feat,
    const float* __restrict__ w0, const float* __restrict__ s0, const float* __restrict__ b0,
    const float* __restrict__ w1, const float* __restrict__ s1, const float* __restrict__ b1,
    const float* __restrict__ w2, const float* __restrict__ s2, const float* __restrict__ b2,
    const int* __restrict__ idxin, const float* __restrict__ newxyz,
    float* __restrict__ outf) {
#pragma clang fp contract(fast)
  __shared__ float xa[32][68];  // layer0 input (3 xyz + 64 feat + 1 zero pad)
  __shared__ float xb[32][64];  // layer1 out; reused as max-reduce buffer
  __shared__ float wt[8192];    // transposed weights of current layer

  const int tid = threadIdx.x;
  const int pair = blockIdx.x;
  const int b = pair >> 10;
  const int s = pair & 1023;

  // ---- gather: 8 threads per sample row ----
  {
    const float cx = newxyz[pair * 3 + 0];
    const float cy = newxyz[pair * 3 + 1];
    const float cz = newxyz[pair * 3 + 2];
    const int n = tid >> 3, k8 = tid & 7;
    const int pid = idxin[pair * NSAMPLE + n];
    const float* fr = feat + ((size_t)(b * NPTS) + pid) * NCH + k8 * 8;
    f4 f0 = *(const f4*)fr;
    f4 f1 = *(const f4*)(fr + 4);
#pragma unroll
    for (int q = 0; q < 4; ++q) xa[n][3 + k8 * 8 + q] = f0[q];
#pragma unroll
    for (int q = 0; q < 4; ++q) xa[n][3 + k8 * 8 + 4 + q] = f1[q];
    if (k8 == 0) {
      const float* pr = xyz + ((size_t)(b * NPTS) + pid) * 3;
      xa[n][0] = pr[0] - cx;
      xa[n][1] = pr[1] - cy;
      xa[n][2] = pr[2] - cz;
      xa[n][67] = 0.f;
    }
  }
  // stage wT0: wt[c*64+o] = w0[o][c], c in [0,68) (c==67 zero pad)
  for (int t = tid; t < 68 * 64; t += 256) {
    int c = t >> 6, o = t & 63;
    wt[t] = (c < 67) ? w0[o * 67 + c] : 0.f;
  }
  __syncthreads();

  const f2 zero2 = f2{0.f, 0.f};

  // ---- layer 1: K=68(pad), 64 out; xa -> xb ; tile 2n x 4o, f2 over o-pairs
  {
    const int ot = tid & 15, nt = tid >> 4;
    f2 acc[2][2] = {};  // [n][opair]
    for (int c = 0; c < 68; c += 4) {
      f4 xq0 = *(const f4*)&xa[nt * 2 + 0][c];
      f4 xq1 = *(const f4*)&xa[nt * 2 + 1][c];
#pragma unroll
      for (int cc = 0; cc < 4; ++cc) {
        f4 wq = *(const f4*)&wt[(c + cc) * 64 + ot * 4];
        f2 wp0 = f2{wq[0], wq[1]};
        f2 wp1 = f2{wq[2], wq[3]};
        f2 x0 = f2{xq0[cc], xq0[cc]};
        f2 x1 = f2{xq1[cc], xq1[cc]};
        acc[0][0] = x0 * wp0 + acc[0][0];
        acc[0][1] = x0 * wp1 + acc[0][1];
        acc[1][0] = x1 * wp0 + acc[1][0];
        acc[1][1] = x1 * wp1 + acc[1][1];
      }
    }
    f2 sc0 = *(const f2*)&s0[ot * 4], sc1 = *(const f2*)&s0[ot * 4 + 2];
    f2 bi0 = *(const f2*)&b0[ot * 4], bi1 = *(const f2*)&b0[ot * 4 + 2];
#pragma unroll
    for (int n = 0; n < 2; ++n) {
      f2 e0 = __builtin_elementwise_max(acc[n][0] * sc0 + bi0, zero2);
      f2 e1 = __builtin_elementwise_max(acc[n][1] * sc1 + bi1, zero2);
      *(f4*)&xb[nt * 2 + n][ot * 4] = f4{e0.x, e0.y, e1.x, e1.y};
    }
  }
  __syncthreads();
  for (int t = tid; t < 64 * 64; t += 256) {
    int c = t >> 6, o = t & 63;
    wt[t] = w1[o * 64 + c];
  }
  __syncthreads();

  // ---- layer 2: K=64, 64 out; xb -> xa ; tile 2n x 4o, f2 over o-pairs ----
  {
    const int ot = tid & 15, nt = tid >> 4;
    f2 acc[2][2] = {};
    for (int c = 0; c < 64; c += 4) {
      f4 xq0 = *(const f4*)&xb[nt * 2 + 0][c];
      f4 xq1 = *(const f4*)&xb[nt * 2 + 1][c];
#pragma unroll
      for (int cc = 0; cc < 4; ++cc) {
        f4 wq = *(const f4*)&wt[(c + cc) * 64 + ot * 4];
        f2 wp0 = f2{wq[0], wq[1]};
        f2 wp1 = f2{wq[2], wq[3]};
        f2 x0 = f2{xq0[cc], xq0[cc]};
        f2 x1 = f2{xq1[cc], xq1[cc]};
        acc[0][0] = x0 * wp0 + acc[0][0];
        acc[0][1] = x0 * wp1 + acc[0][1];
        acc[1][0] = x1 * wp0 + acc[1][0];
        acc[1][1] = x1 * wp1 + acc[1][1];
      }
    }
    f2 sc0 = *(const f2*)&s1[ot * 4], sc1 = *(const f2*)&s1[ot * 4 + 2];
    f2 bi0 = *(const f2*)&b1[ot * 4], bi1 = *(const f2*)&b1[ot * 4 + 2];
#pragma unroll
    for (int n = 0; n < 2; ++n) {
      f2 e0 = __builtin_elementwise_max(acc[n][0] * sc0 + bi0, zero2);
      f2 e1 = __builtin_elementwise_max(acc[n][1] * sc1 + bi1, zero2);
      *(f4*)&xa[nt * 2 + n][ot * 4] = f4{e0.x, e0.y, e1.x, e1.y};
    }
  }
  __syncthreads();
  for (int t = tid; t < 64 * 128; t += 256) {
    int c = t >> 7, o = t & 127;
    wt[t] = w2[o * 64 + c];
  }
  __syncthreads();

  // ---- layer 3: K=64, 128 out; xa -> max over 4 n ; tile 4n x 4o packed ---
  {
    const int ot = tid & 31, nt = tid >> 5;
    f2 acc[4][2] = {};
    for (int c = 0; c < 64; c += 4) {
      f4 xq[4];
#pragma unroll
      for (int j = 0; j < 4; ++j) xq[j] = *(const f4*)&xa[nt * 4 + j][c];
#pragma unroll
      for (int cc = 0; cc < 4; ++cc) {
        f4 wq = *(const f4*)&wt[(c + cc) * 128 + ot * 4];
        f2 wp0 = f2{wq[0], wq[1]};
        f2 wp1 = f2{wq[2], wq[3]};
#pragma unroll
        for (int j = 0; j < 4; ++j) {
          f2 xs = f2{xq[j][cc], xq[j][cc]};
          acc[j][0] = xs * wp0 + acc[j][0];
          acc[j][1] = xs * wp1 + acc[j][1];
        }
      }
    }
    f2 sc0 = *(const f2*)&s2[ot * 4], sc1 = *(const f2*)&s2[ot * 4 + 2];
    f2 bi0 = *(const f2*)&b2[ot * 4], bi1 = *(const f2*)&b2[ot * 4 + 2];
    f2 mx0, mx1;
#pragma unroll
    for (int j = 0; j < 4; ++j) {
      f2 v0 = __builtin_elementwise_max(acc[j][0] * sc0 + bi0, zero2);
      f2 v1 = __builtin_elementwise_max(acc[j][1] * sc1 + bi1, zero2);
      if (j == 0) { mx0 = v0; mx1 = v1; }
      else {
        mx0 = __builtin_elementwise_max(mx0, v0);
        mx1 = __builtin_elementwise_max(mx1, v1);
      }
    }
    float* red = &xb[0][0];  // xb free after layer2 barrier
    *(f4*)&red[nt * 128 + ot * 4] = f4{mx0.x, mx0.y, mx1.x, mx1.y};
    __syncthreads();
    if (tid < 128) {
      float m = red[tid];
#pragma unroll
      for (int w = 1; w < 8; ++w) m = fmaxf(m, red[w * 128 + tid]);
      outf[((size_t)(b * 128 + tid)) * 1024 + s] = m;
    }
  }
}

extern "C" void kernel_launch(void* const* d_in, const int* in_sizes, int n_in,
                              void* d_out, int out_size, void* d_ws, size_t ws_size,
                              hipStream_t stream) {
  const float* xyz = (const float*)d_in[0];
  const float* feat = (const float*)d_in[1];
  const float* w0 = (const float*)d_in[2];
  const float* s0 = (const float*)d_in[3];
  const float* b0 = (const float*)d_in[4];
  const float* w1 = (const float*)d_in[5];
  const float* s1 = (const float*)d_in[6];
  const float* b1 = (const float*)d_in[7];
  const float* w2 = (const float*)d_in[8];
  const float* s2 = (const float*)d_in[9];
  const float* b2 = (const float*)d_in[10];

  float* newxyz = (float*)d_out;                    // (8,1024,3)
  float* outf = (float*)d_out + BATCH * NPOINT * 3; // (8,128,1024)
  int* idxws = (int*)d_ws;                          // (8*1024, 32) ints = 1 MB

  fps_kernel<<<BATCH, 256, 0, stream>>>(xyz, newxyz);
  ball_kernel<<<(BATCH * NPOINT) / 4, 256, 0, stream>>>(xyz, newxyz, idxws);
  group_mlp_kernel<<<BATCH * NPOINT, 256, 0, stream>>>(
      xyz, feat, w0, s0, b0, w1, s1, b1, w2, s2, b2, idxws, newxyz, outf);
}

// Round 9
// 1403.220 us; speedup vs baseline: 1.1322x; 1.0143x over previous
//
#include <hip/hip_runtime.h>

#define BATCH 8
#define NPTS 8192
#define NCH 64
#define NPOINT 1024
#define NSAMPLE 32
#define G 8  // groups per MLP block

typedef float f4 __attribute__((ext_vector_type(4)));
typedef float f2 __attribute__((ext_vector_type(2)));

// DPP-based u64 max step: merge with the value DPP-shifted across lanes.
// bound_ctrl=false + old=self => invalid-source lanes self-merge (no-op).
template <int CTRL>
__device__ __forceinline__ unsigned long long dpp_max_u64(unsigned long long k) {
  int lo = (int)(unsigned int)k;
  int hi = (int)(unsigned int)(k >> 32);
  int slo = __builtin_amdgcn_update_dpp(lo, lo, CTRL, 0xf, 0xf, false);
  int shi = __builtin_amdgcn_update_dpp(hi, hi, CTRL, 0xf, 0xf, false);
  unsigned long long s =
      ((unsigned long long)(unsigned int)shi << 32) | (unsigned int)slo;
  return (s > k) ? s : k;
}

// ---------------------------------------------------------------------------
// Furthest point sampling — EXACT R6 structure (measured 1042 us, absmax 0.0).
// 256 threads (4 waves, 1/SIMD) is the empirical optimum: R4 1024thr=1322,
// R6 256thr=1042, R7 512thr=1194 — the tail is block-convergent, extra waves
// only add merge work and barrier skew.
// ---------------------------------------------------------------------------
__global__ __launch_bounds__(256) void fps_kernel(const float* __restrict__ xyz,
                                                  float* __restrict__ newxyz) {
  const int b = blockIdx.x;
  const int tid = threadIdx.x;
  const int lane = tid & 63;
  const int wid = tid >> 6;  // 0..3
  const float* xb = xyz + (size_t)b * NPTS * 3;

  __shared__ float px_l[NPTS], py_l[NPTS], pz_l[NPTS];        // 96 KB SoA
  __shared__ __align__(16) unsigned long long pke[2][4][4];   // key, xy, z, pad
  __shared__ unsigned short winidx[NPOINT];

  // coalesced global -> LDS staging (lane-adjacent p => conflict-free writes)
  for (int p = tid; p < NPTS; p += 256) {
    px_l[p] = xb[p * 3 + 0];
    py_l[p] = xb[p * 3 + 1];
    pz_l[p] = xb[p * 3 + 2];
  }
  __syncthreads();

  // register fill from LDS: thread owns pairs (2t+512j, 2t+512j+1)
  f2 pxv[16], pyv[16], pzv[16], mindv[16];
#pragma unroll
  for (int j = 0; j < 16; ++j) {
    int p = 2 * tid + 512 * j;
    pxv[j] = *(const f2*)&px_l[p];
    pyv[j] = *(const f2*)&py_l[p];
    pzv[j] = *(const f2*)&pz_l[p];
    mindv[j] = f2{1e10f, 1e10f};
  }
  float qx = px_l[0], qy = py_l[0], qz = pz_l[0];  // pivot = point 0

  for (int i = 1; i < NPOINT; ++i) {
#pragma clang fp contract(off)
    const int par = i & 1;
    f2 qx2 = f2{qx, qx}, qy2 = f2{qy, qy}, qz2 = f2{qz, qz};

    // distance update (exact ref order) + value-only pk-max tree
    f2 tmax;
#pragma unroll
    for (int j = 0; j < 16; ++j) {
      f2 dx = pxv[j] - qx2;
      f2 dy = pyv[j] - qy2;
      f2 dz = pzv[j] - qz2;
      f2 d = (dx * dx + dy * dy) + dz * dz;
      f2 m = __builtin_elementwise_min(mindv[j], d);
      mindv[j] = m;
      tmax = (j == 0) ? m : __builtin_elementwise_max(tmax, m);
    }
    float lmax = fmaxf(tmax.x, tmax.y);

    // thread-local lowest global index achieving lmax
    // global idx = 2*tid + 512*j + k; scan j desc, y(k=1) then x(k=0)
    int c = 0;
#pragma unroll
    for (int j = 15; j >= 0; --j) {
      if (mindv[j].y == lmax) c = 2 * j + 1;
      if (mindv[j].x == lmax) c = 2 * j;
    }
    unsigned int gidx = (unsigned int)(2 * tid + ((c >> 1) << 9) + (c & 1));
    unsigned long long key =
        ((unsigned long long)__float_as_uint(lmax) << 32) |
        (unsigned long long)(~gidx);

    // wave argmax via DPP (VALU-speed), result valid in lane 63
    key = dpp_max_u64<0x111>(key);  // row_shr:1
    key = dpp_max_u64<0x112>(key);  // row_shr:2
    key = dpp_max_u64<0x114>(key);  // row_shr:4
    key = dpp_max_u64<0x118>(key);  // row_shr:8
    key = dpp_max_u64<0x142>(key);  // row_bcast:15
    key = dpp_max_u64<0x143>(key);  // row_bcast:31

    if (lane == 63) {
      unsigned int widx = ~(unsigned int)key;
      float wx = px_l[widx], wy = py_l[widx], wz = pz_l[widx];
      ulonglong2 e0;
      e0.x = key;
      e0.y = ((unsigned long long)__float_as_uint(wy) << 32) |
             (unsigned long long)__float_as_uint(wx);
      *(ulonglong2*)&pke[par][wid][0] = e0;
      pke[par][wid][2] = (unsigned long long)__float_as_uint(wz);
    }
    __syncthreads();

    // merge the 4 wave entries (broadcast LDS reads, b128)
    const ulonglong2* ew = (const ulonglong2*)&pke[par][0][0];
    ulonglong2 m0 = ew[0];                 // {key, xy}
    unsigned long long bz = ew[1].x;       // {z, pad}
#pragma unroll
    for (int w = 1; w < 4; ++w) {
      ulonglong2 t = ew[2 * w];
      unsigned long long tz = ew[2 * w + 1].x;
      if (t.x > m0.x) { m0 = t; bz = tz; }
    }
    qx = __uint_as_float((unsigned int)m0.y);
    qy = __uint_as_float((unsigned int)(m0.y >> 32));
    qz = __uint_as_float((unsigned int)bz);
    if (tid == 0) winidx[i] = (unsigned short)(~(unsigned int)m0.x);
  }

  __syncthreads();
  // write all 1024 sampled points from LDS
  for (int t = tid; t < NPOINT; t += 256) {
    const int idx = (t == 0) ? 0 : (int)winidx[t];
    float* op = newxyz + b * (NPOINT * 3) + t * 3;
    op[0] = px_l[idx];
    op[1] = py_l[idx];
    op[2] = pz_l[idx];
  }
}

// ---------------------------------------------------------------------------
// Ball query: one wave per (b, s) center. Ordered scan, first 32 indices with
// d2 < r^2; pad with first hit (0 if none). Exact fp32 distance arithmetic.
// ---------------------------------------------------------------------------
__global__ __launch_bounds__(256) void ball_kernel(const float* __restrict__ xyz,
                                                   const float* __restrict__ newxyz,
                                                   int* __restrict__ idxout) {
  const int lane = threadIdx.x & 63;
  const int pair = blockIdx.x * 4 + (threadIdx.x >> 6);
  const int b = pair >> 10;
  const float cx = newxyz[pair * 3 + 0];
  const float cy = newxyz[pair * 3 + 1];
  const float cz = newxyz[pair * 3 + 2];
  const float* xb = xyz + (size_t)b * NPTS * 3;
  int* op = idxout + pair * NSAMPLE;

  int cnt = 0;
  int first = 0;
  for (int base = 0; base < NPTS && cnt < NSAMPLE; base += 64) {
    const int p = base + lane;
    const float* pp = xb + p * 3;
    float dx = __fsub_rn(cx, pp[0]);
    float dy = __fsub_rn(cy, pp[1]);
    float dz = __fsub_rn(cz, pp[2]);
    float d2 = __fadd_rn(__fadd_rn(__fmul_rn(dx, dx), __fmul_rn(dy, dy)),
                         __fmul_rn(dz, dz));
    bool pred = d2 < 0.04f;  // strict <, RADIUS^2 in fp32
    unsigned long long m = __ballot(pred);
    if (cnt == 0 && m) first = base + __builtin_ctzll(m);
    int rank = cnt + (int)__popcll(m & ((1ull << lane) - 1ull));
    if (pred && rank < NSAMPLE) op[rank] = p;
    cnt += (int)__popcll(m);
  }
  if (cnt < NSAMPLE) {
    for (int r = cnt + lane; r < NSAMPLE; r += 64) op[r] = first;
  }
}

// ---------------------------------------------------------------------------
// Group + 3-layer MLP + max-pool, G=8 groups per block (grid 1024).
// R8 post-mortem: per-group weight re-staging (50 KB x 8192 blocks = 410 MB),
// 6 barriers/group, dependent gather and 4KB-strided output writes dominated,
// not FMA issue. This version:
//  - ALL weights staged in LDS once per block (66.5 KB), reused by 8 groups
//  - scale/bias hoisted to registers once
//  - gather for group g+1 prefetched into registers during group g compute
//  - outputs staged in obuf[128][8], written once as 32B-contiguous f4 chunks
//  - 4 barriers per group
// LDS: wt 16640 + xa 2176 + xb 2048 + obuf 1024 floats = 85.5 KB -> 1 blk/CU.
// pk-f2 inner loops with fma contraction (R8-verified absmax 0.0).
// ---------------------------------------------------------------------------
__global__ __launch_bounds__(256) void group_mlp_kernel(
    const float* __restrict__ xyz, const float* __restrict__ feat,
    const float* __restrict__ w0, const float* __restrict__ s0, const float* __restrict__ b0,
    const float* __restrict__ w1, const float* __restrict__ s1, const float* __restrict__ b1,
    const float* __restrict__ w2, const float* __restrict__ s2, const float* __restrict__ b2,
    const int* __restrict__ idxin, const float* __restrict__ newxyz,
    float* __restrict__ outf) {
#pragma clang fp contract(fast)
  __shared__ float wt0[68 * 64];   // [c][o], c padded to 68 (zeros)
  __shared__ float wt1[64 * 64];   // [c][o]
  __shared__ float wt2[64 * 128];  // [c][o]
  __shared__ float xa[32][68];
  __shared__ float xb[32][64];     // also reused as max-reduce buffer
  __shared__ float obuf[128 * G];  // [ch][g]

  const int tid = threadIdx.x;
  const int pair0 = blockIdx.x * G;
  const int b = pair0 >> 10;
  const int sbase = pair0 & 1023;

  // stage all three weight matrices once (transposed)
  for (int t = tid; t < 68 * 64; t += 256) {
    int c = t >> 6, o = t & 63;
    wt0[t] = (c < 67) ? w0[o * 67 + c] : 0.f;
  }
  for (int t = tid; t < 64 * 64; t += 256) {
    int c = t >> 6, o = t & 63;
    wt1[t] = w1[o * 64 + c];
  }
  for (int t = tid; t < 64 * 128; t += 256) {
    int c = t >> 7, o = t & 127;
    wt2[t] = w2[o * 64 + c];
  }

  // hoist scale/bias (constant across groups)
  const int ot2 = tid & 15;  // layers 1,2 output tile
  const int ot3 = tid & 31;  // layer 3 output tile
  const f2 sA0 = *(const f2*)&s0[ot2 * 4], sA1 = *(const f2*)&s0[ot2 * 4 + 2];
  const f2 bA0 = *(const f2*)&b0[ot2 * 4], bA1 = *(const f2*)&b0[ot2 * 4 + 2];
  const f2 sB0 = *(const f2*)&s1[ot2 * 4], sB1 = *(const f2*)&s1[ot2 * 4 + 2];
  const f2 bB0 = *(const f2*)&b1[ot2 * 4], bB1 = *(const f2*)&b1[ot2 * 4 + 2];
  const f2 sC0 = *(const f2*)&s2[ot3 * 4], sC1 = *(const f2*)&s2[ot3 * 4 + 2];
  const f2 bC0 = *(const f2*)&b2[ot3 * 4], bC1 = *(const f2*)&b2[ot3 * 4 + 2];

  // gather lane mapping: 8 threads per sample row
  const int gn = tid >> 3, gk = tid & 7;

  // prefetch group 0 into registers
  f4 pf0, pf1;
  float pxr = 0.f, pyr = 0.f, pzr = 0.f, cxr = 0.f, cyr = 0.f, czr = 0.f;
  {
    const int pid = idxin[pair0 * NSAMPLE + gn];
    const float* fr = feat + ((size_t)(b * NPTS) + pid) * NCH + gk * 8;
    pf0 = *(const f4*)fr;
    pf1 = *(const f4*)(fr + 4);
    if (gk == 0) {
      const float* pr = xyz + ((size_t)(b * NPTS) + pid) * 3;
      pxr = pr[0]; pyr = pr[1]; pzr = pr[2];
      cxr = newxyz[pair0 * 3 + 0];
      cyr = newxyz[pair0 * 3 + 1];
      czr = newxyz[pair0 * 3 + 2];
    }
  }
  __syncthreads();  // weights ready

  const f2 zero2 = f2{0.f, 0.f};

  for (int g = 0; g < G; ++g) {
    // ---- write xa from prefetched registers ----
#pragma unroll
    for (int q = 0; q < 4; ++q) xa[gn][3 + gk * 8 + q] = pf0[q];
#pragma unroll
    for (int q = 0; q < 4; ++q) xa[gn][3 + gk * 8 + 4 + q] = pf1[q];
    if (gk == 0) {
      xa[gn][0] = pxr - cxr;
      xa[gn][1] = pyr - cyr;
      xa[gn][2] = pzr - czr;
      xa[gn][67] = 0.f;
    }
    __syncthreads();  // b1: xa ready (also fences prior obuf-reduce reads)

    // ---- prefetch next group's gather (overlaps 3 compute phases) ----
    if (g + 1 < G) {
      const int pairg = pair0 + g + 1;
      const int pid = idxin[pairg * NSAMPLE + gn];
      const float* fr = feat + ((size_t)(b * NPTS) + pid) * NCH + gk * 8;
      pf0 = *(const f4*)fr;
      pf1 = *(const f4*)(fr + 4);
      if (gk == 0) {
        const float* pr = xyz + ((size_t)(b * NPTS) + pid) * 3;
        pxr = pr[0]; pyr = pr[1]; pzr = pr[2];
        cxr = newxyz[pairg * 3 + 0];
        cyr = newxyz[pairg * 3 + 1];
        czr = newxyz[pairg * 3 + 2];
      }
    }

    // ---- layer 1: K=68(pad), 64 out; xa -> xb ----
    {
      const int nt = tid >> 4;
      f2 acc[2][2] = {};
      for (int c = 0; c < 68; c += 4) {
        f4 xq0 = *(const f4*)&xa[nt * 2 + 0][c];
        f4 xq1 = *(const f4*)&xa[nt * 2 + 1][c];
#pragma unroll
        for (int cc = 0; cc < 4; ++cc) {
          f4 wq = *(const f4*)&wt0[(c + cc) * 64 + ot2 * 4];
          f2 wp0 = f2{wq[0], wq[1]};
          f2 wp1 = f2{wq[2], wq[3]};
          f2 x0 = f2{xq0[cc], xq0[cc]};
          f2 x1 = f2{xq1[cc], xq1[cc]};
          acc[0][0] = x0 * wp0 + acc[0][0];
          acc[0][1] = x0 * wp1 + acc[0][1];
          acc[1][0] = x1 * wp0 + acc[1][0];
          acc[1][1] = x1 * wp1 + acc[1][1];
        }
      }
#pragma unroll
      for (int n = 0; n < 2; ++n) {
        f2 e0 = __builtin_elementwise_max(acc[n][0] * sA0 + bA0, zero2);
        f2 e1 = __builtin_elementwise_max(acc[n][1] * sA1 + bA1, zero2);
        *(f4*)&xb[nt * 2 + n][ot2 * 4] = f4{e0.x, e0.y, e1.x, e1.y};
      }
    }
    __syncthreads();  // b2

    // ---- layer 2: K=64, 64 out; xb -> xa ----
    {
      const int nt = tid >> 4;
      f2 acc[2][2] = {};
      for (int c = 0; c < 64; c += 4) {
        f4 xq0 = *(const f4*)&xb[nt * 2 + 0][c];
        f4 xq1 = *(const f4*)&xb[nt * 2 + 1][c];
#pragma unroll
        for (int cc = 0; cc < 4; ++cc) {
          f4 wq = *(const f4*)&wt1[(c + cc) * 64 + ot2 * 4];
          f2 wp0 = f2{wq[0], wq[1]};
          f2 wp1 = f2{wq[2], wq[3]};
          f2 x0 = f2{xq0[cc], xq0[cc]};
          f2 x1 = f2{xq1[cc], xq1[cc]};
          acc[0][0] = x0 * wp0 + acc[0][0];
          acc[0][1] = x0 * wp1 + acc[0][1];
          acc[1][0] = x1 * wp0 + acc[1][0];
          acc[1][1] = x1 * wp1 + acc[1][1];
        }
      }
#pragma unroll
      for (int n = 0; n < 2; ++n) {
        f2 e0 = __builtin_elementwise_max(acc[n][0] * sB0 + bB0, zero2);
        f2 e1 = __builtin_elementwise_max(acc[n][1] * sB1 + bB1, zero2);
        *(f4*)&xa[nt * 2 + n][ot2 * 4] = f4{e0.x, e0.y, e1.x, e1.y};
      }
    }
    __syncthreads();  // b3

    // ---- layer 3: K=64, 128 out; xa -> max over 4 n -> red -> obuf ----
    {
      const int nt = tid >> 5;
      f2 acc[4][2] = {};
      for (int c = 0; c < 64; c += 4) {
        f4 xq[4];
#pragma unroll
        for (int j = 0; j < 4; ++j) xq[j] = *(const f4*)&xa[nt * 4 + j][c];
#pragma unroll
        for (int cc = 0; cc < 4; ++cc) {
          f4 wq = *(const f4*)&wt2[(c + cc) * 128 + ot3 * 4];
          f2 wp0 = f2{wq[0], wq[1]};
          f2 wp1 = f2{wq[2], wq[3]};
#pragma unroll
          for (int j = 0; j < 4; ++j) {
            f2 xs = f2{xq[j][cc], xq[j][cc]};
            acc[j][0] = xs * wp0 + acc[j][0];
            acc[j][1] = xs * wp1 + acc[j][1];
          }
        }
      }
      f2 mx0, mx1;
#pragma unroll
      for (int j = 0; j < 4; ++j) {
        f2 v0 = __builtin_elementwise_max(acc[j][0] * sC0 + bC0, zero2);
        f2 v1 = __builtin_elementwise_max(acc[j][1] * sC1 + bC1, zero2);
        if (j == 0) { mx0 = v0; mx1 = v1; }
        else {
          mx0 = __builtin_elementwise_max(mx0, v0);
          mx1 = __builtin_elementwise_max(mx1, v1);
        }
      }
      float* red = &xb[0][0];  // xb free after L2 reads
      *(f4*)&red[nt * 128 + ot3 * 4] = f4{mx0.x, mx0.y, mx1.x, mx1.y};
    }
    __syncthreads();  // b4
    if (tid < 128) {
      float* red = &xb[0][0];
      float m = red[tid];
#pragma unroll
      for (int w = 1; w < 8; ++w) m = fmaxf(m, red[w * 128 + tid]);
      obuf[tid * G + g] = m;
    }
    // next iteration's b1 fences these obuf/red reads vs xb re-write
  }

  __syncthreads();
  // final coalesced output write: thread -> (ch, half), 16B each
  {
    const int ch = tid >> 1, h = tid & 1;
    f4 v = *(const f4*)&obuf[ch * G + h * 4];
    *(f4*)&outf[((size_t)(b * 128 + ch)) * 1024 + sbase + h * 4] = v;
  }
}

extern "C" void kernel_launch(void* const* d_in, const int* in_sizes, int n_in,
                              void* d_out, int out_size, void* d_ws, size_t ws_size,
                              hipStream_t stream) {
  const float* xyz = (const float*)d_in[0];
  const float* feat = (const float*)d_in[1];
  const float* w0 = (const float*)d_in[2];
  const float* s0 = (const float*)d_in[3];
  const float* b0 = (const float*)d_in[4];
  const float* w1 = (const float*)d_in[5];
  const float* s1 = (const float*)d_in[6];
  const float* b1 = (const float*)d_in[7];
  const float* w2 = (const float*)d_in[8];
  const float* s2 = (const float*)d_in[9];
  const float* b2 = (const float*)d_in[10];

  float* newxyz = (float*)d_out;                    // (8,1024,3)
  float* outf = (float*)d_out + BATCH * NPOINT * 3; // (8,128,1024)
  int* idxws = (int*)d_ws;                          // (8*1024, 32) ints = 1 MB

  fps_kernel<<<BATCH, 256, 0, stream>>>(xyz, newxyz);
  ball_kernel<<<(BATCH * NPOINT) / 4, 256, 0, stream>>>(xyz, newxyz, idxws);
  group_mlp_kernel<<<(BATCH * NPOINT) / G, 256, 0, stream>>>(
      xyz, feat, w0, s0, b0, w1, s1, b1, w2, s2, b2, idxws, newxyz, outf);
}

// Round 10
// 1191.714 us; speedup vs baseline: 1.3331x; 1.1775x over previous
//
#include <hip/hip_runtime.h>

#define BATCH 8
#define NPTS 8192
#define NCH 64
#define NPOINT 1024
#define NSAMPLE 32
#define G 16  // groups per MLP block

typedef float f4 __attribute__((ext_vector_type(4)));
typedef float f2 __attribute__((ext_vector_type(2)));
typedef _Float16 h8 __attribute__((ext_vector_type(8)));

// DPP-based u64 max step: merge with the value DPP-shifted across lanes.
template <int CTRL>
__device__ __forceinline__ unsigned long long dpp_max_u64(unsigned long long k) {
  int lo = (int)(unsigned int)k;
  int hi = (int)(unsigned int)(k >> 32);
  int slo = __builtin_amdgcn_update_dpp(lo, lo, CTRL, 0xf, 0xf, false);
  int shi = __builtin_amdgcn_update_dpp(hi, hi, CTRL, 0xf, 0xf, false);
  unsigned long long s =
      ((unsigned long long)(unsigned int)shi << 32) | (unsigned int)slo;
  return (s > k) ? s : k;
}

// ---------------------------------------------------------------------------
// Furthest point sampling — EXACT R6 structure (measured 1042 us, absmax 0.0).
// 256 threads (4 waves, 1/SIMD) is the empirical optimum of this family.
// ---------------------------------------------------------------------------
__global__ __launch_bounds__(256) void fps_kernel(const float* __restrict__ xyz,
                                                  float* __restrict__ newxyz) {
  const int b = blockIdx.x;
  const int tid = threadIdx.x;
  const int lane = tid & 63;
  const int wid = tid >> 6;  // 0..3
  const float* xb = xyz + (size_t)b * NPTS * 3;

  __shared__ float px_l[NPTS], py_l[NPTS], pz_l[NPTS];        // 96 KB SoA
  __shared__ __align__(16) unsigned long long pke[2][4][4];   // key, xy, z, pad
  __shared__ unsigned short winidx[NPOINT];

  for (int p = tid; p < NPTS; p += 256) {
    px_l[p] = xb[p * 3 + 0];
    py_l[p] = xb[p * 3 + 1];
    pz_l[p] = xb[p * 3 + 2];
  }
  __syncthreads();

  f2 pxv[16], pyv[16], pzv[16], mindv[16];
#pragma unroll
  for (int j = 0; j < 16; ++j) {
    int p = 2 * tid + 512 * j;
    pxv[j] = *(const f2*)&px_l[p];
    pyv[j] = *(const f2*)&py_l[p];
    pzv[j] = *(const f2*)&pz_l[p];
    mindv[j] = f2{1e10f, 1e10f};
  }
  float qx = px_l[0], qy = py_l[0], qz = pz_l[0];  // pivot = point 0

  for (int i = 1; i < NPOINT; ++i) {
#pragma clang fp contract(off)
    const int par = i & 1;
    f2 qx2 = f2{qx, qx}, qy2 = f2{qy, qy}, qz2 = f2{qz, qz};

    f2 tmax;
#pragma unroll
    for (int j = 0; j < 16; ++j) {
      f2 dx = pxv[j] - qx2;
      f2 dy = pyv[j] - qy2;
      f2 dz = pzv[j] - qz2;
      f2 d = (dx * dx + dy * dy) + dz * dz;
      f2 m = __builtin_elementwise_min(mindv[j], d);
      mindv[j] = m;
      tmax = (j == 0) ? m : __builtin_elementwise_max(tmax, m);
    }
    float lmax = fmaxf(tmax.x, tmax.y);

    int c = 0;
#pragma unroll
    for (int j = 15; j >= 0; --j) {
      if (mindv[j].y == lmax) c = 2 * j + 1;
      if (mindv[j].x == lmax) c = 2 * j;
    }
    unsigned int gidx = (unsigned int)(2 * tid + ((c >> 1) << 9) + (c & 1));
    unsigned long long key =
        ((unsigned long long)__float_as_uint(lmax) << 32) |
        (unsigned long long)(~gidx);

    key = dpp_max_u64<0x111>(key);  // row_shr:1
    key = dpp_max_u64<0x112>(key);  // row_shr:2
    key = dpp_max_u64<0x114>(key);  // row_shr:4
    key = dpp_max_u64<0x118>(key);  // row_shr:8
    key = dpp_max_u64<0x142>(key);  // row_bcast:15
    key = dpp_max_u64<0x143>(key);  // row_bcast:31

    if (lane == 63) {
      unsigned int widx = ~(unsigned int)key;
      float wx = px_l[widx], wy = py_l[widx], wz = pz_l[widx];
      ulonglong2 e0;
      e0.x = key;
      e0.y = ((unsigned long long)__float_as_uint(wy) << 32) |
             (unsigned long long)__float_as_uint(wx);
      *(ulonglong2*)&pke[par][wid][0] = e0;
      pke[par][wid][2] = (unsigned long long)__float_as_uint(wz);
    }
    __syncthreads();

    const ulonglong2* ew = (const ulonglong2*)&pke[par][0][0];
    ulonglong2 m0 = ew[0];
    unsigned long long bz = ew[1].x;
#pragma unroll
    for (int w = 1; w < 4; ++w) {
      ulonglong2 t = ew[2 * w];
      unsigned long long tz = ew[2 * w + 1].x;
      if (t.x > m0.x) { m0 = t; bz = tz; }
    }
    qx = __uint_as_float((unsigned int)m0.y);
    qy = __uint_as_float((unsigned int)(m0.y >> 32));
    qz = __uint_as_float((unsigned int)bz);
    if (tid == 0) winidx[i] = (unsigned short)(~(unsigned int)m0.x);
  }

  __syncthreads();
  for (int t = tid; t < NPOINT; t += 256) {
    const int idx = (t == 0) ? 0 : (int)winidx[t];
    float* op = newxyz + b * (NPOINT * 3) + t * 3;
    op[0] = px_l[idx];
    op[1] = py_l[idx];
    op[2] = pz_l[idx];
  }
}

// ---------------------------------------------------------------------------
// Ball query: one wave per (b, s) center. Unchanged (exact fp32).
// ---------------------------------------------------------------------------
__global__ __launch_bounds__(256) void ball_kernel(const float* __restrict__ xyz,
                                                   const float* __restrict__ newxyz,
                                                   int* __restrict__ idxout) {
  const int lane = threadIdx.x & 63;
  const int pair = blockIdx.x * 4 + (threadIdx.x >> 6);
  const int b = pair >> 10;
  const float cx = newxyz[pair * 3 + 0];
  const float cy = newxyz[pair * 3 + 1];
  const float cz = newxyz[pair * 3 + 2];
  const float* xb = xyz + (size_t)b * NPTS * 3;
  int* op = idxout + pair * NSAMPLE;

  int cnt = 0;
  int first = 0;
  for (int base = 0; base < NPTS && cnt < NSAMPLE; base += 64) {
    const int p = base + lane;
    const float* pp = xb + p * 3;
    float dx = __fsub_rn(cx, pp[0]);
    float dy = __fsub_rn(cy, pp[1]);
    float dz = __fsub_rn(cz, pp[2]);
    float d2 = __fadd_rn(__fadd_rn(__fmul_rn(dx, dx), __fmul_rn(dy, dy)),
                         __fmul_rn(dz, dz));
    bool pred = d2 < 0.04f;
    unsigned long long m = __ballot(pred);
    if (cnt == 0 && m) first = base + __builtin_ctzll(m);
    int rank = cnt + (int)__popcll(m & ((1ull << lane) - 1ull));
    if (pred && rank < NSAMPLE) op[rank] = p;
    cnt += (int)__popcll(m);
  }
  if (cnt < NSAMPLE) {
    for (int r = cnt + lane; r < NSAMPLE; r += 64) op[r] = first;
  }
}

// ---------------------------------------------------------------------------
// Group + 3-layer MLP + max-pool via f16 MFMA. G=16 groups/block, grid 512.
// R9 post-mortem: MLP bound by per-FMA LDS weight reads + VALU issue — fixed
// by v_mfma_f32_16x16x32_f16 with ALL weights as register-resident
// B-fragments (36 VGPR/thread, loaded+f16-converted once per block; weight
// LDS traffic = 0). Layouts (HW-verified m89/m120):
//   A[m=lane&15][k=quad*8+j]  B[k=quad*8+j][n=lane&15]
//   C col=lane&15, row=quad*4+reg
// K-permutation for layer1: cols 0-63 = feat, 64-66 = xyz, 67-95 = zero pad
// (weights permuted identically). Activations ping-pong x0(104h)/x1/x2(72h
// strides -> conflict-free 16-row b128 reads). 3 barriers/group. fp32 accum;
// f16 inputs/weights (tolerance 5.4e-2 >> expected ~1e-2 error).
// Wave w: L1/L2 n-tile w; L3 n-tiles w and w+4. Max-pool: reg max over rows
// + 2x shfl_xor across quads -> obuf[128][G] -> one coalesced write.
// ---------------------------------------------------------------------------
__global__ __launch_bounds__(256) void group_mlp_kernel(
    const float* __restrict__ xyz, const float* __restrict__ feat,
    const float* __restrict__ w0, const float* __restrict__ s0, const float* __restrict__ b0,
    const float* __restrict__ w1, const float* __restrict__ s1, const float* __restrict__ b1,
    const float* __restrict__ w2, const float* __restrict__ s2, const float* __restrict__ b2,
    const int* __restrict__ idxin, const float* __restrict__ newxyz,
    float* __restrict__ outf) {
  __shared__ _Float16 x0[32 * 104];  // layer1 input, K-padded to 96
  __shared__ _Float16 x1[32 * 72];   // layer2 input
  __shared__ _Float16 x2[32 * 72];   // layer3 input
  __shared__ float obuf[128 * G];

  const int tid = threadIdx.x;
  const int lane = tid & 63;
  const int wv = tid >> 6;       // wave 0..3
  const int qd = lane >> 4;      // quad 0..3
  const int col = lane & 15;
  const int pair0 = blockIdx.x * G;
  const int b = pair0 >> 10;
  const int sbase = pair0 & 1023;

  // ---- build register-resident B-fragments (once per block) ----
  h8 bf1[3], bf2[2], bf3[2][2];
  {
    const int o1 = wv * 16 + col;  // L1/L2 channel for this lane
#pragma unroll
    for (int t = 0; t < 3; ++t) {
#pragma unroll
      for (int j = 0; j < 8; ++j) {
        int kp = t * 32 + qd * 8 + j;  // permuted K index
        float v = 0.f;
        if (kp < 64) v = w0[o1 * 67 + 3 + kp];
        else if (kp < 67) v = w0[o1 * 67 + (kp - 64)];
        bf1[t][j] = (_Float16)v;
      }
    }
#pragma unroll
    for (int t = 0; t < 2; ++t) {
#pragma unroll
      for (int j = 0; j < 8; ++j) {
        int k = t * 32 + qd * 8 + j;
        bf2[t][j] = (_Float16)w1[o1 * 64 + k];
      }
    }
#pragma unroll
    for (int u = 0; u < 2; ++u) {
      const int o3 = (wv + 4 * u) * 16 + col;
#pragma unroll
      for (int t = 0; t < 2; ++t) {
#pragma unroll
        for (int j = 0; j < 8; ++j) {
          int k = t * 32 + qd * 8 + j;
          bf3[u][t][j] = (_Float16)w2[o3 * 64 + k];
        }
      }
    }
  }
  // hoisted scale/bias (per-lane channel)
  const int o12 = wv * 16 + col;
  const float sA = s0[o12], bA = b0[o12];
  const float sB = s1[o12], bB = b1[o12];
  const float sC0 = s2[o12], bC0 = b2[o12];
  const float sC1 = s2[o12 + 64], bC1 = b2[o12 + 64];

  // zero the pad region of x0 (cols 64..103; 64-66 rewritten per group)
  for (int t = tid; t < 32 * 40; t += 256) {
    x0[(t / 40) * 104 + 64 + (t % 40)] = (_Float16)0.f;
  }

  // gather mapping: 8 threads per sample row
  const int gn = tid >> 3, gk = tid & 7;

  // prefetch group 0
  f4 pf0, pf1;
  float pxr = 0.f, pyr = 0.f, pzr = 0.f, cxr = 0.f, cyr = 0.f, czr = 0.f;
  {
    const int pid = idxin[pair0 * NSAMPLE + gn];
    const float* fr = feat + ((size_t)(b * NPTS) + pid) * NCH + gk * 8;
    pf0 = *(const f4*)fr;
    pf1 = *(const f4*)(fr + 4);
    if (gk == 0) {
      const float* pr = xyz + ((size_t)(b * NPTS) + pid) * 3;
      pxr = pr[0]; pyr = pr[1]; pzr = pr[2];
      cxr = newxyz[pair0 * 3 + 0];
      cyr = newxyz[pair0 * 3 + 1];
      czr = newxyz[pair0 * 3 + 2];
    }
  }

  for (int g = 0; g < G; ++g) {
    // ---- write x0 from prefetched registers (feat cols 0-63, xyz 64-66) ---
    {
      h8 hv;
#pragma unroll
      for (int q = 0; q < 4; ++q) {
        hv[q] = (_Float16)pf0[q];
        hv[4 + q] = (_Float16)pf1[q];
      }
      *(h8*)&x0[gn * 104 + gk * 8] = hv;
      if (gk == 0) {
        x0[gn * 104 + 64] = (_Float16)(pxr - cxr);
        x0[gn * 104 + 65] = (_Float16)(pyr - cyr);
        x0[gn * 104 + 66] = (_Float16)(pzr - czr);
      }
    }
    __syncthreads();  // bar A: x0 ready (also fences prior iter's x0 reads)

    // ---- prefetch next group's gather ----
    if (g + 1 < G) {
      const int pairg = pair0 + g + 1;
      const int pid = idxin[pairg * NSAMPLE + gn];
      const float* fr = feat + ((size_t)(b * NPTS) + pid) * NCH + gk * 8;
      pf0 = *(const f4*)fr;
      pf1 = *(const f4*)(fr + 4);
      if (gk == 0) {
        const float* pr = xyz + ((size_t)(b * NPTS) + pid) * 3;
        pxr = pr[0]; pyr = pr[1]; pzr = pr[2];
        cxr = newxyz[pairg * 3 + 0];
        cyr = newxyz[pairg * 3 + 1];
        czr = newxyz[pairg * 3 + 2];
      }
    }

    // ---- layer 1: x0 (32x96) @ bf1 -> x1 (f16) ----
    {
      f4 a0 = {0.f, 0.f, 0.f, 0.f}, a1 = a0;
#pragma unroll
      for (int t = 0; t < 3; ++t) {
        h8 fa0 = *(const h8*)&x0[col * 104 + t * 32 + qd * 8];
        h8 fa1 = *(const h8*)&x0[(16 + col) * 104 + t * 32 + qd * 8];
        a0 = __builtin_amdgcn_mfma_f32_16x16x32_f16(fa0, bf1[t], a0, 0, 0, 0);
        a1 = __builtin_amdgcn_mfma_f32_16x16x32_f16(fa1, bf1[t], a1, 0, 0, 0);
      }
#pragma unroll
      for (int r = 0; r < 4; ++r) {
        float v0 = fmaxf(fmaf(a0[r], sA, bA), 0.f);
        float v1 = fmaxf(fmaf(a1[r], sA, bA), 0.f);
        x1[(qd * 4 + r) * 72 + o12] = (_Float16)v0;
        x1[(16 + qd * 4 + r) * 72 + o12] = (_Float16)v1;
      }
    }
    __syncthreads();  // bar B: x1 ready

    // ---- layer 2: x1 (32x64) @ bf2 -> x2 (f16) ----
    {
      f4 a0 = {0.f, 0.f, 0.f, 0.f}, a1 = a0;
#pragma unroll
      for (int t = 0; t < 2; ++t) {
        h8 fa0 = *(const h8*)&x1[col * 72 + t * 32 + qd * 8];
        h8 fa1 = *(const h8*)&x1[(16 + col) * 72 + t * 32 + qd * 8];
        a0 = __builtin_amdgcn_mfma_f32_16x16x32_f16(fa0, bf2[t], a0, 0, 0, 0);
        a1 = __builtin_amdgcn_mfma_f32_16x16x32_f16(fa1, bf2[t], a1, 0, 0, 0);
      }
#pragma unroll
      for (int r = 0; r < 4; ++r) {
        float v0 = fmaxf(fmaf(a0[r], sB, bB), 0.f);
        float v1 = fmaxf(fmaf(a1[r], sB, bB), 0.f);
        x2[(qd * 4 + r) * 72 + o12] = (_Float16)v0;
        x2[(16 + qd * 4 + r) * 72 + o12] = (_Float16)v1;
      }
    }
    __syncthreads();  // bar C: x2 ready

    // ---- layer 3: x2 (32x64) @ bf3[u] -> relu -> max over 32 rows ----
    {
      f4 c00 = {0.f, 0.f, 0.f, 0.f}, c01 = c00, c10 = c00, c11 = c00;
#pragma unroll
      for (int t = 0; t < 2; ++t) {
        h8 fa0 = *(const h8*)&x2[col * 72 + t * 32 + qd * 8];
        h8 fa1 = *(const h8*)&x2[(16 + col) * 72 + t * 32 + qd * 8];
        c00 = __builtin_amdgcn_mfma_f32_16x16x32_f16(fa0, bf3[0][t], c00, 0, 0, 0);
        c01 = __builtin_amdgcn_mfma_f32_16x16x32_f16(fa1, bf3[0][t], c01, 0, 0, 0);
        c10 = __builtin_amdgcn_mfma_f32_16x16x32_f16(fa0, bf3[1][t], c10, 0, 0, 0);
        c11 = __builtin_amdgcn_mfma_f32_16x16x32_f16(fa1, bf3[1][t], c11, 0, 0, 0);
      }
      float mx0 = 0.f, mx1 = 0.f;  // relu output >= 0
#pragma unroll
      for (int r = 0; r < 4; ++r) {
        mx0 = fmaxf(mx0, fmaxf(fmaf(c00[r], sC0, bC0), 0.f));
        mx0 = fmaxf(mx0, fmaxf(fmaf(c01[r], sC0, bC0), 0.f));
        mx1 = fmaxf(mx1, fmaxf(fmaf(c10[r], sC1, bC1), 0.f));
        mx1 = fmaxf(mx1, fmaxf(fmaf(c11[r], sC1, bC1), 0.f));
      }
      // max across quads (lanes col, col+16, col+32, col+48)
      mx0 = fmaxf(mx0, __shfl_xor(mx0, 16));
      mx0 = fmaxf(mx0, __shfl_xor(mx0, 32));
      mx1 = fmaxf(mx1, __shfl_xor(mx1, 16));
      mx1 = fmaxf(mx1, __shfl_xor(mx1, 32));
      if (lane < 16) {
        obuf[o12 * G + g] = mx0;
        obuf[(o12 + 64) * G + g] = mx1;
      }
    }
    // loop-top bar A fences x2 reads vs next x0 writes (different buffers ok)
  }

  __syncthreads();
  // final coalesced output write: thread -> (ch, 8-wide half of G)
  {
    const int ch = tid >> 1, hb = (tid & 1) * 8;
    f4 v0 = *(const f4*)&obuf[ch * G + hb];
    f4 v1 = *(const f4*)&obuf[ch * G + hb + 4];
    float* dst = &outf[((size_t)(b * 128 + ch)) * 1024 + sbase + hb];
    *(f4*)dst = v0;
    *(f4*)(dst + 4) = v1;
  }
}

extern "C" void kernel_launch(void* const* d_in, const int* in_sizes, int n_in,
                              void* d_out, int out_size, void* d_ws, size_t ws_size,
                              hipStream_t stream) {
  const float* xyz = (const float*)d_in[0];
  const float* feat = (const float*)d_in[1];
  const float* w0 = (const float*)d_in[2];
  const float* s0 = (const float*)d_in[3];
  const float* b0 = (const float*)d_in[4];
  const float* w1 = (const float*)d_in[5];
  const float* s1 = (const float*)d_in[6];
  const float* b1 = (const float*)d_in[7];
  const float* w2 = (const float*)d_in[8];
  const float* s2 = (const float*)d_in[9];
  const float* b2 = (const float*)d_in[10];

  float* newxyz = (float*)d_out;                    // (8,1024,3)
  float* outf = (float*)d_out + BATCH * NPOINT * 3; // (8,128,1024)
  int* idxws = (int*)d_ws;                          // (8*1024, 32) ints = 1 MB

  fps_kernel<<<BATCH, 256, 0, stream>>>(xyz, newxyz);
  ball_kernel<<<(BATCH * NPOINT) / 4, 256, 0, stream>>>(xyz, newxyz, idxws);
  group_mlp_kernel<<<(BATCH * NPOINT) / G, 256, 0, stream>>>(
      xyz, feat, w0, s0, b0, w1, s1, b1, w2, s2, b2, idxws, newxyz, outf);
}